// Round 11
// baseline (446.599 us; speedup 1.0000x reference)
//
#include <hip/hip_runtime.h>
#include <math.h>

#define NMAPS 16
#define DIN 512
#define DOUT 128
#define QD 64

#define VST 164  // Vall column stride (floats): 164 % 32 == 4 -> staggered banks
#define TST 20   // per-t sub-stride: t*20 % 32 spread {0,20,8,28,16,4,24,12}

typedef __attribute__((ext_vector_type(8))) short bf16x8;  // 8 bf16 (4 VGPR)
typedef __attribute__((ext_vector_type(4))) float f32x4;

// bf16 split helpers (RNE). x = bf2f(hi) + bf2f(lo) + O(2^-18 |x|).
__device__ __forceinline__ unsigned short f2bf(float x) {
  unsigned int u = __float_as_uint(x);
  return (unsigned short)((u + 0x7FFFu + ((u >> 16) & 1u)) >> 16);
}
__device__ __forceinline__ float bf2f(unsigned short h) {
  return __uint_as_float(((unsigned int)h) << 16);
}

// DPP lane^1 / lane^2 within quad (VALU pipe).
__device__ __forceinline__ float qxor1(float x) {  // quad_perm {1,0,3,2}
  return __int_as_float(__builtin_amdgcn_update_dpp(
      0, __float_as_int(x), 0xB1, 0xF, 0xF, true));
}
__device__ __forceinline__ float qxor2(float x) {  // quad_perm {2,3,0,1}
  return __int_as_float(__builtin_amdgcn_update_dpp(
      0, __float_as_int(x), 0x4E, 0xF, 0xF, true));
}
// Butterfly sum over the 8-lane group. All 8 lanes of a group are always
// active together (c is group-uniform), so this is divergence-safe in 2b.
__device__ __forceinline__ float groupSum8(float x) {
  x += qxor1(x);
  x += qxor2(x);
  x += __int_as_float(__builtin_amdgcn_ds_swizzle(
      __float_as_int(x), 0x101F));  // xor 4
  return x;
}

// slarfg sign convention (LAPACK) — unchanged since R4.
__device__ __forceinline__ void make_tau(float xn2, float alpha, float& tau,
                                         float& invs) {
  if (xn2 == 0.f) { tau = 0.f; invs = 0.f; }
  else {
    float mag = sqrtf(alpha * alpha + xn2);
    float beta = (alpha >= 0.f) ? -mag : mag;
    tau = (beta - alpha) / beta;
    invs = 1.f / (alpha - beta);
  }
}

// 4x4 blocked tree dot over 16 elements.
__device__ __forceinline__ float tree_dot16(const float (&x)[16],
                                            const float (&y)[16]) {
  float pp[4] = {0.f, 0.f, 0.f, 0.f};
#pragma unroll
  for (int q = 0; q < 4; ++q)
#pragma unroll
    for (int k = 0; k < 4; ++k)
      pp[q] = fmaf(x[4 * q + k], y[4 * q + k], pp[q]);
  return ((pp[0] + pp[1]) + pp[2]) + pp[3];
}

// Masked norm^2 over rows r = t+8k > piv, tree-reduced.
__device__ __forceinline__ float tree_norm_gt16(const float (&a)[16],
                                                const int t, const int piv) {
  float ss[4] = {0.f, 0.f, 0.f, 0.f};
#pragma unroll
  for (int q = 0; q < 4; ++q)
#pragma unroll
    for (int k = 0; k < 4; ++k) {
      int kk = 4 * q + k;
      int r = t + 8 * kk;
      if (r > piv) ss[q] = fmaf(a[kk], a[kk], ss[q]);
    }
  return ((ss[0] + ss[1]) + ss[2]) + ss[3];
}

template <bool SCALE>
__device__ __forceinline__ void publish_col16(float (&a)[16], const int t,
                                              const int piv, const float invs,
                                              float* __restrict__ Vrow) {
#pragma unroll
  for (int k4 = 0; k4 < 4; ++k4) {
    float4 v4;
    float* vv = (float*)&v4;
#pragma unroll
    for (int e = 0; e < 4; ++e) {
      int k = 4 * k4 + e;
      int r = t + 8 * k;
      float nv;
      if (r > piv) {
        if (SCALE) a[k] *= invs;
        nv = a[k];
      } else nv = (r == piv) ? 1.f : 0.f;
      vv[e] = nv;
    }
    *(float4*)&Vrow[4 * k4] = v4;
  }
}

__device__ __forceinline__ void load_v16(float (&vr)[16],
                                         const float* __restrict__ Vrow) {
#pragma unroll
  for (int k4 = 0; k4 < 4; ++k4) {
    float4 v4 = *(const float4*)&Vrow[4 * k4];
    vr[4 * k4 + 0] = v4.x; vr[4 * k4 + 1] = v4.y;
    vr[4 * k4 + 2] = v4.z; vr[4 * k4 + 3] = v4.w;
  }
}

// ---------------- pre-split kernels (write d_ws; fragment-order layout) -------
__global__ __launch_bounds__(256) void presplit_w(const float* __restrict__ W,
                                                  unsigned short* __restrict__ Wp) {
  int id = blockIdx.x * 256 + threadIdx.x;
  int row = id & 127;
  int fg = (id >> 7) & 3;
  int mc = id >> 9;
  int mm = mc >> 4, ch = mc & 15;
  const float* src = W + ((size_t)mm * DOUT + row) * DIN + ch * 32 + fg * 8;
  bf16x8 hi, lo;
  unsigned short* hp = (unsigned short*)&hi;
  unsigned short* lp = (unsigned short*)&lo;
#pragma unroll
  for (int e = 0; e < 8; ++e) {
    float v = src[e];
    unsigned short h = f2bf(v);
    hp[e] = h;
    lp[e] = f2bf(v - bf2f(h));
  }
  unsigned short* dst = Wp + (size_t)mc * 8192 + (fg * 128 + row) * 8;
  *(bf16x8*)dst = hi;
  *(bf16x8*)(dst + 4096) = lo;
}

__global__ __launch_bounds__(256) void presplit_x(const float* __restrict__ X,
                                                  unsigned short* __restrict__ Xp) {
  int id = blockIdx.x * 256 + threadIdx.x;
  int col = id & 63;
  int fg = (id >> 6) & 3;
  int bc = id >> 8;
  int bb = bc >> 4, ch = bc & 15;
  const float* src = X + ((size_t)bb * DIN + ch * 32 + fg * 8) * QD + col;
  bf16x8 hi, lo;
  unsigned short* hp = (unsigned short*)&hi;
  unsigned short* lp = (unsigned short*)&lo;
#pragma unroll
  for (int e = 0; e < 8; ++e) {
    float v = src[(size_t)e * QD];
    unsigned short h = f2bf(v);
    hp[e] = h;
    lp[e] = f2bf(v - bf2f(h));
  }
  unsigned short* dst = Xp + (size_t)bc * 4096 + (fg * 64 + col) * 8;
  *(bf16x8*)dst = hi;
  *(bf16x8*)(dst + 2048) = lo;
}

// One block (512 thr = 8 waves) per matrix (m,b).
// GEMM: direct-fragment MFMA (pre-split d_ws arrays), no LDS staging.
// 2a: sequential sgeqr2, 1 barrier/step, publish-ahead into persistent Vall.
// 2b: BARRIER-FREE — V is static after 2a; each 8-lane group builds its own
//   Q column by applying reflectors j = c-1..0 from Vall (bitwise-identical
//   arithmetic to the old backward org2r trailing-update order per column).
// Handoff/store: 4-chunk Buf[32][68] round-trips (256B-coalesced global I/O).
template <bool PRE>
__global__ __launch_bounds__(512, 6) void frmap_qr(
    const float* __restrict__ X, const float* __restrict__ W,
    float* __restrict__ out, const unsigned short* __restrict__ Wp,
    const unsigned short* __restrict__ Xp) {
  __shared__ __align__(16) float Buf[32][68];
  __shared__ __align__(16) float Vall[QD * VST];  // v_j at Vall[j*VST + t*TST + k]
  __shared__ float Tau[QD];

  const int tid = threadIdx.x;
  const int l = tid & 63;
  const int w = __builtin_amdgcn_readfirstlane(tid >> 6);  // wave 0..7
  const int rg = w >> 1;  // GEMM row-group (rows 32rg..32rg+31)
  const int cg = w & 1;   // GEMM col-group (cols 32cg..32cg+31)
  const int c = tid >> 3; // QR column 0..63
  const int t = tid & 7;  // QR row class (rows t+8k)
  const int fr = l & 15;
  const int fg = l >> 4;

  const int bid = blockIdx.x;  // m*256 + b
  const int m = bid >> 8;
  const int b = bid & 255;
  const float* Xb = X + (size_t)b * (DIN * QD);
  const float* Wm = W + (size_t)m * (DOUT * DIN);

  f32x4 acc[2][2];
#pragma unroll
  for (int tr = 0; tr < 2; ++tr)
#pragma unroll
    for (int tc = 0; tc < 2; ++tc)
      acc[tr][tc] = (f32x4){0.f, 0.f, 0.f, 0.f};

  if constexpr (PRE) {
    const char* wsrc = (const char*)Wp + (size_t)(m * 16) * 16384;
    const char* xsrc = (const char*)Xp + (size_t)(b * 16) * 8192;
    const int woff = (fg * 128 + 32 * rg + fr) * 16;
    const int xoff = (fg * 64 + 32 * cg + fr) * 16;
    for (int ch = 0; ch < 16; ++ch) {
      bf16x8 ah0 = *(const bf16x8*)(wsrc + woff);
      bf16x8 al0 = *(const bf16x8*)(wsrc + 8192 + woff);
      bf16x8 ah1 = *(const bf16x8*)(wsrc + woff + 256);
      bf16x8 al1 = *(const bf16x8*)(wsrc + 8192 + woff + 256);
      bf16x8 bh0 = *(const bf16x8*)(xsrc + xoff);
      bf16x8 bl0 = *(const bf16x8*)(xsrc + 4096 + xoff);
      bf16x8 bh1 = *(const bf16x8*)(xsrc + xoff + 256);
      bf16x8 bl1 = *(const bf16x8*)(xsrc + 4096 + xoff + 256);
      acc[0][0] = __builtin_amdgcn_mfma_f32_16x16x32_bf16(ah0, bh0, acc[0][0], 0, 0, 0);
      acc[0][0] = __builtin_amdgcn_mfma_f32_16x16x32_bf16(ah0, bl0, acc[0][0], 0, 0, 0);
      acc[0][0] = __builtin_amdgcn_mfma_f32_16x16x32_bf16(al0, bh0, acc[0][0], 0, 0, 0);
      acc[0][1] = __builtin_amdgcn_mfma_f32_16x16x32_bf16(ah0, bh1, acc[0][1], 0, 0, 0);
      acc[0][1] = __builtin_amdgcn_mfma_f32_16x16x32_bf16(ah0, bl1, acc[0][1], 0, 0, 0);
      acc[0][1] = __builtin_amdgcn_mfma_f32_16x16x32_bf16(al0, bh1, acc[0][1], 0, 0, 0);
      acc[1][0] = __builtin_amdgcn_mfma_f32_16x16x32_bf16(ah1, bh0, acc[1][0], 0, 0, 0);
      acc[1][0] = __builtin_amdgcn_mfma_f32_16x16x32_bf16(ah1, bl0, acc[1][0], 0, 0, 0);
      acc[1][0] = __builtin_amdgcn_mfma_f32_16x16x32_bf16(al1, bh0, acc[1][0], 0, 0, 0);
      acc[1][1] = __builtin_amdgcn_mfma_f32_16x16x32_bf16(ah1, bh1, acc[1][1], 0, 0, 0);
      acc[1][1] = __builtin_amdgcn_mfma_f32_16x16x32_bf16(ah1, bl1, acc[1][1], 0, 0, 0);
      acc[1][1] = __builtin_amdgcn_mfma_f32_16x16x32_bf16(al1, bh1, acc[1][1], 0, 0, 0);
      wsrc += 16384;
      xsrc += 8192;
    }
  } else {
    for (int ch = 0; ch < 16; ++ch) {
      int kc = ch * 32;
      bf16x8 ah[2], al[2], bh[2], bl[2];
#pragma unroll
      for (int tr = 0; tr < 2; ++tr) {
        const float* ws = Wm + (size_t)(32 * rg + 16 * tr + fr) * DIN + kc + 8 * fg;
        float4 v0 = *(const float4*)ws;
        float4 v1 = *(const float4*)(ws + 4);
        float p[8] = {v0.x, v0.y, v0.z, v0.w, v1.x, v1.y, v1.z, v1.w};
        unsigned short* hp = (unsigned short*)&ah[tr];
        unsigned short* lp = (unsigned short*)&al[tr];
#pragma unroll
        for (int e = 0; e < 8; ++e) {
          unsigned short h = f2bf(p[e]);
          hp[e] = h;
          lp[e] = f2bf(p[e] - bf2f(h));
        }
      }
#pragma unroll
      for (int tc = 0; tc < 2; ++tc) {
        const float* xs = Xb + (size_t)(kc + 8 * fg) * QD + 32 * cg + 16 * tc + fr;
        unsigned short* hp = (unsigned short*)&bh[tc];
        unsigned short* lp = (unsigned short*)&bl[tc];
#pragma unroll
        for (int e = 0; e < 8; ++e) {
          float v = xs[(size_t)e * QD];
          unsigned short h = f2bf(v);
          hp[e] = h;
          lp[e] = f2bf(v - bf2f(h));
        }
      }
#pragma unroll
      for (int tr = 0; tr < 2; ++tr)
#pragma unroll
        for (int tc = 0; tc < 2; ++tc) {
          acc[tr][tc] = __builtin_amdgcn_mfma_f32_16x16x32_bf16(ah[tr], bh[tc], acc[tr][tc], 0, 0, 0);
          acc[tr][tc] = __builtin_amdgcn_mfma_f32_16x16x32_bf16(ah[tr], bl[tc], acc[tr][tc], 0, 0, 0);
          acc[tr][tc] = __builtin_amdgcn_mfma_f32_16x16x32_bf16(al[tr], bh[tc], acc[tr][tc], 0, 0, 0);
        }
    }
  }

  // ---------------- Phase 1.5: acc -> Buf -> QR ownership (4 chunks of 32 rows)
  // C/D layout (m89): col = 32cg+16tc+(lane&15), local row = 16tr + 4fg + reg.
  float a[16];
#pragma unroll
  for (int q = 0; q < 4; ++q) {
    if (q) __syncthreads();  // Buf reuse fence
    if (rg == q) {
#pragma unroll
      for (int tr = 0; tr < 2; ++tr)
#pragma unroll
        for (int tc = 0; tc < 2; ++tc)
#pragma unroll
          for (int v = 0; v < 4; ++v)
            Buf[16 * tr + 4 * fg + v][32 * cg + 16 * tc + fr] = acc[tr][tc][v];
    }
    __syncthreads();
#pragma unroll
    for (int k = 4 * q; k < 4 * q + 4; ++k) a[k] = Buf[t + 8 * k - 32 * q][c];
  }

  // ---------------- prologue: group c==0 makes tau0/invs0, scales, publishes
  if (c == 0) {
    float myalpha = 0.f;
#pragma unroll
    for (int k = 0; k < 16; ++k)
      if (t + 8 * k == 0) myalpha = a[k];
    float xn2 = groupSum8(tree_norm_gt16(a, t, 0));
    float alpha = groupSum8(myalpha);  // exact: zeros elsewhere
    float tau, invs;
    make_tau(xn2, alpha, tau, invs);
    if (t == 0) Tau[0] = tau;
    publish_col16<true>(a, t, 0, invs, &Vall[0 * VST + t * TST]);
  }
  __syncthreads();  // B0: V_0 / Tau[0] visible

  // ---------------- Phase 2a: sgeqr2 (1 barrier/step, publish-ahead)
  for (int j = 0; j < QD - 1; ++j) {
    if (c > j) {
      float taul = Tau[j];
      float vr[16];
      load_v16(vr, &Vall[j * VST + t * TST]);  // uniform col -> broadcast reads
      float wv = taul * groupSum8(tree_dot16(vr, a));
#pragma unroll
      for (int k = 0; k < 16; ++k) a[k] = fmaf(-wv, vr[k], a[k]);
      if (c == j + 1) {  // tail: next pivot's tau/scale/publish
        float myalpha = 0.f;
#pragma unroll
        for (int k = 0; k < 16; ++k)
          if (t + 8 * k == j + 1) myalpha = a[k];  // static reg index
        float xn2 = groupSum8(tree_norm_gt16(a, t, j + 1));
        float alpha = groupSum8(myalpha);
        float tau, invs;
        make_tau(xn2, alpha, tau, invs);
        if (t == 0) Tau[j + 1] = tau;
        publish_col16<true>(a, t, j + 1, invs, &Vall[(j + 1) * VST + t * TST]);
      }
    }
    __syncthreads();  // fences V_{j+1}, Tau[j+1]
  }
  __syncthreads();  // phase boundary: all of Vall/Tau visible to 2b

  // ---------------- Phase 2b: barrier-free per-column forward build.
  // Column c: u = e_c - tau_c v_c, then apply H_j for j = c-1..0 — the exact
  // reflector order and dot/reduce arithmetic of the old backward org2r.
  {
    float tauc = Tau[c];
#pragma unroll
    for (int k = 0; k < 16; ++k) {  // formation from own v_c (in registers)
      int r = t + 8 * k;
      float val = a[k];
      float nv;
      if (r == c) nv = 1.f - tauc;
      else if (r < c) nv = 0.f;
      else nv = -tauc * val;
      a[k] = nv;
    }
    for (int j = c - 1; j >= 0; --j) {  // divergent across groups; lanes of a
      float taul = Tau[j];              // group share c -> butterfly is safe
      float vr[16];
      load_v16(vr, &Vall[j * VST + t * TST]);
      float wv = taul * groupSum8(tree_dot16(vr, a));
#pragma unroll
      for (int k = 0; k < 16; ++k) a[k] = fmaf(-wv, vr[k], a[k]);
    }
  }

  // ---------------- Phase 3: store via Buf, 4 chunks (256B-coalesced)
  float* O = out + (size_t)bid * (DOUT * QD);
#pragma unroll
  for (int q = 0; q < 4; ++q) {
    if (q) __syncthreads();  // Buf reuse fence
#pragma unroll
    for (int k = 4 * q; k < 4 * q + 4; ++k) Buf[t + 8 * k - 32 * q][c] = a[k];
    __syncthreads();         // also fences 2b stragglers before first read
#pragma unroll
    for (int i = 0; i < 4; ++i) {
      int r = 4 * w + i;     // 8 waves x 4 rows = 32 rows
      O[(32 * q + r) * QD + l] = Buf[r][l];
    }
  }
}

extern "C" void kernel_launch(void* const* d_in, const int* in_sizes, int n_in,
                              void* d_out, int out_size, void* d_ws, size_t ws_size,
                              hipStream_t stream) {
  const float* X = (const float*)d_in[0];   // (256, 512, 64) fp32
  const float* W = (const float*)d_in[1];   // (16, 128, 512) fp32
  float* out = (float*)d_out;               // (4096, 128, 64) fp32

  const size_t needW = (size_t)NMAPS * 16 * 16384;  // 4 MiB
  const size_t needX = (size_t)256 * 16 * 8192;     // 32 MiB
  if (ws_size >= needW + needX) {
    unsigned short* Wp = (unsigned short*)d_ws;
    unsigned short* Xp = (unsigned short*)((char*)d_ws + needW);
    presplit_w<<<512, 256, 0, stream>>>(W, Wp);
    presplit_x<<<4096, 256, 0, stream>>>(X, Xp);
    frmap_qr<true><<<NMAPS * 256, 512, 0, stream>>>(X, W, out, Wp, Xp);
  } else {
    frmap_qr<false><<<NMAPS * 256, 512, 0, stream>>>(X, W, out, nullptr, nullptr);
  }
}